// Round 1
// baseline (195.813 us; speedup 1.0000x reference)
//
#include <hip/hip_runtime.h>
#include <math.h>

#define S_ 2
#define N_ 32
#define I_ 4096
#define D_ 128
#define K_ 16
#define C_ 16               // chunks per (s,n) slice
#define P_ (I_ / C_)        // 256 points per block
#define THREADS 256
#define WAVES 4             // THREADS/64

// Order-preserving float<->uint encoding: unsigned compare on enc(f)
// matches float compare on f. enc(x) > 0 for every non-NaN float,
// so a zeroed buffer is the identity for atomicMax.
__device__ __forceinline__ unsigned enc(float f) {
    unsigned b = __float_as_uint(f);
    return (b & 0x80000000u) ? ~b : (b | 0x80000000u);
}
__device__ __forceinline__ float dec(unsigned u) {
    unsigned b = (u & 0x80000000u) ? (u ^ 0x80000000u) : ~u;
    return __uint_as_float(b);
}

__global__ __launch_bounds__(THREADS) void maxpool_main(
    const float* __restrict__ F,      // [S, N, I, D]
    const int*   __restrict__ IDX,    // [S, N*I], value = n*K + local
    unsigned*    __restrict__ OUT)    // [S, N, K, D] encoded uints (pre-zeroed)
{
    __shared__ float acc[WAVES * K_ * D_];   // 32 KiB: per-wave private [K][D]
    __shared__ int   kidx[P_];

    const int blk  = blockIdx.x;        // [0, S*N*C)
    const int c    = blk % C_;
    const int sn   = blk / C_;          // slice index s*N + n
    const int base = c * P_;
    const int tid  = threadIdx.x;

    // init private accumulators to -inf
    #pragma unroll
    for (int i = tid; i < WAVES * K_ * D_; i += THREADS) acc[i] = -INFINITY;
    // local cluster id per point (value mod K, since offsets are multiples of K)
    kidx[tid] = IDX[sn * I_ + base + tid] & (K_ - 1);
    __syncthreads();

    const int w    = tid >> 6;
    const int lane = tid & 63;
    float* priv = acc + w * (K_ * D_);
    const float2* src = (const float2*)(F + (size_t)(sn * I_ + base) * D_);

    // one wave = one point per iteration; 64 lanes x float2 = full 128-float row
    #pragma unroll 4
    for (int it = 0; it < P_ / WAVES; ++it) {
        const int p = it * WAVES + w;
        const int k = kidx[p];                        // LDS broadcast read
        const float2 v = src[(size_t)p * (D_ / 2) + lane];
        float2* a = (float2*)(priv + k * D_ + lane * 2);
        float2 o = *a;
        o.x = fmaxf(o.x, v.x);
        o.y = fmaxf(o.y, v.y);
        *a = o;                                       // same wave: no race
    }
    __syncthreads();

    // reduce the 4 wave-private copies and push to global via uint atomicMax
    unsigned* dst = OUT + (size_t)sn * (K_ * D_);
    #pragma unroll
    for (int e = tid; e < K_ * D_; e += THREADS) {
        float m = fmaxf(fmaxf(acc[e],            acc[e + K_ * D_]),
                        fmaxf(acc[e + 2 * K_ * D_], acc[e + 3 * K_ * D_]));
        atomicMax(&dst[e], enc(m));
    }
}

__global__ __launch_bounds__(256) void maxpool_decode(unsigned* __restrict__ OUT) {
    const int i = blockIdx.x * 256 + threadIdx.x;
    const unsigned u = OUT[i];
    ((float*)OUT)[i] = (u == 0u) ? -INFINITY : dec(u);
}

extern "C" void kernel_launch(void* const* d_in, const int* in_sizes, int n_in,
                              void* d_out, int out_size, void* d_ws, size_t ws_size,
                              hipStream_t stream) {
    const float* F   = (const float*)d_in[0];
    const int*   IDX = (const int*)d_in[1];
    unsigned*    OUT = (unsigned*)d_out;

    // identity for encoded atomicMax is 0
    hipMemsetAsync(d_out, 0, (size_t)out_size * sizeof(float), stream);

    maxpool_main<<<S_ * N_ * C_, THREADS, 0, stream>>>(F, IDX, OUT);
    maxpool_decode<<<out_size / 256, 256, 0, stream>>>(OUT);
}

// Round 2
// 194.974 us; speedup vs baseline: 1.0043x; 1.0043x over previous
//
#include <hip/hip_runtime.h>
#include <math.h>

#define S_ 2
#define N_ 32
#define I_ 4096
#define D_ 128
#define K_ 16
#define C_ 16               // chunks per (s,n) slice
#define P_ (I_ / C_)        // 256 points per block
#define THREADS 256
#define WAVES 4             // THREADS/64
#define KD (K_ * D_)        // 2048 floats per partial

// Stage 1: each block reduces 256 points of one slice into a [K][D] partial.
// Per-wave private LDS accumulators (no LDS atomics, no races: one point per
// wave per iteration, 64 lanes x float2 covers the full 128-float row).
__global__ __launch_bounds__(THREADS) void maxpool_main(
    const float* __restrict__ F,      // [S, N, I, D]
    const int*   __restrict__ IDX,    // [S, N*I], value = n*K + local
    float*       __restrict__ WS)     // [S*N*C, K*D] partials (every elt written)
{
    __shared__ float acc[WAVES * KD];   // 32 KiB: per-wave private [K][D]
    __shared__ int   kidx[P_];

    const int blk  = blockIdx.x;        // blk = sn*C + c
    const int c    = blk % C_;
    const int sn   = blk / C_;
    const int base = c * P_;
    const int tid  = threadIdx.x;

    #pragma unroll
    for (int i = tid; i < WAVES * KD; i += THREADS) acc[i] = -INFINITY;
    // local cluster id (value mod K; offsets are multiples of K)
    kidx[tid] = IDX[sn * I_ + base + tid] & (K_ - 1);
    __syncthreads();

    const int w    = tid >> 6;
    const int lane = tid & 63;
    float* priv = acc + w * KD;
    const float2* src = (const float2*)(F + (size_t)(sn * I_ + base) * D_);

    #pragma unroll 4
    for (int it = 0; it < P_ / WAVES; ++it) {
        const int p = it * WAVES + w;
        const int k = kidx[p];                        // LDS broadcast read
        const float2 v = src[(size_t)p * (D_ / 2) + lane];
        float2* a = (float2*)(priv + k * D_ + lane * 2);
        float2 o = *a;
        o.x = fmaxf(o.x, v.x);
        o.y = fmaxf(o.y, v.y);
        *a = o;                                       // same wave: no race
    }
    __syncthreads();

    // reduce the 4 wave-private copies, write partial (plain stores, no atomics)
    float* dst = WS + (size_t)blk * KD;
    #pragma unroll
    for (int e = tid; e < KD; e += THREADS) {
        float m = fmaxf(fmaxf(acc[e],          acc[e + KD]),
                        fmaxf(acc[e + 2 * KD], acc[e + 3 * KD]));
        dst[e] = m;
    }
}

// Stage 2: max over the C=16 chunk-partials per slice -> d_out.
__global__ __launch_bounds__(256) void maxpool_combine(
    const float* __restrict__ WS,     // [S*N, C, K*D]
    float*       __restrict__ OUT)    // [S*N, K*D]
{
    const int i  = blockIdx.x * 256 + threadIdx.x;   // [0, S*N*K*D)
    const int sn = i >> 11;                          // / KD
    const int e  = i & (KD - 1);
    const float* p = WS + ((size_t)sn * C_) * KD + e;
    float m = -INFINITY;
    #pragma unroll
    for (int c = 0; c < C_; ++c) m = fmaxf(m, p[(size_t)c * KD]);
    OUT[i] = m;
}

extern "C" void kernel_launch(void* const* d_in, const int* in_sizes, int n_in,
                              void* d_out, int out_size, void* d_ws, size_t ws_size,
                              hipStream_t stream) {
    const float* F   = (const float*)d_in[0];
    const int*   IDX = (const int*)d_in[1];
    float*       WS  = (float*)d_ws;
    float*       OUT = (float*)d_out;

    maxpool_main<<<S_ * N_ * C_, THREADS, 0, stream>>>(F, IDX, WS);
    maxpool_combine<<<(S_ * N_ * KD) / 256, 256, 0, stream>>>(WS, OUT);
}